// Round 5
// baseline (3595.362 us; speedup 1.0000x reference)
//
#include <hip/hip_runtime.h>
#include <hip/hip_bf16.h>

// ViT forward, MI355X. 256xBN GEMM with counted-vmcnt half-tile pipeline
// (T3/T4: 3 half-stages in flight, never drain to 0) + T2 XOR swizzle +
// T5 setprio. Fused flash attention. f32 residual/LN. Adaptive ws chunking.

typedef unsigned short u16;
typedef __hip_bfloat16 bf16;
typedef __bf16 bf16x8 __attribute__((ext_vector_type(8)));
typedef float f32x4 __attribute__((ext_vector_type(4)));

typedef const __attribute__((address_space(1))) void* gas_ptr;
typedef __attribute__((address_space(3))) void* las_ptr;

#define TOKENS 577
#define TPAD   640
#define DMODEL 512
#define SM_SCALE 0.08838834764831845f   /* 128^-0.5 */

static __device__ __forceinline__ u16 f2b(float v) {
    bf16 t = __float2bfloat16(v);
    return *(u16*)&t;
}

__device__ __forceinline__ void vwait(int n) {
    switch (n) {
        case 0: asm volatile("s_waitcnt vmcnt(0)" ::: "memory"); break;
        case 3: asm volatile("s_waitcnt vmcnt(3)" ::: "memory"); break;
        case 4: asm volatile("s_waitcnt vmcnt(4)" ::: "memory"); break;
        case 6: asm volatile("s_waitcnt vmcnt(6)" ::: "memory"); break;
        default: asm volatile("s_waitcnt vmcnt(8)" ::: "memory"); break;
    }
}

// ---------------------------------------------------------------------------
// GEMM C[M,N] = A[M,K] @ Bt[N,K]^T (+bias)(+gelu). BM=256, BN in {128,256}.
// 512 threads = 8 waves (2M x 4N). BK=64 split in two K-halves of 32.
// Pipeline: 3 half-stages in flight, counted vmcnt, 2 raw barriers/K-tile.
// LDS swizzle: (row, slot s of 8 k-elems) holds global octet s ^ ((row>>1)&3);
// achieved by pre-swizzling the per-lane GLOBAL source (gload_lds dst linear).
// OUTMODE 0: C row = m.  OUTMODE 1: patch-embed (row remap b*577+1+t, +pos).
// ---------------------------------------------------------------------------
template<int OUTMODE, bool GELU, int BN>
__global__ __launch_bounds__(512, 1)
void gemm2(const u16* __restrict__ A, int lda,
           const u16* __restrict__ Bt, int ldb,
           float* __restrict__ Cf, bf16* __restrict__ Cb, int ldc,
           const float* __restrict__ bias, const float* __restrict__ pos,
           int K, int rows_valid)
{
    constexpr int FN = BN / 64;          // B fragments per wave (4 or 2)
    constexpr int BH = BN / 128;         // B gloads per thread per half (2 or 1)
    constexpr int L  = 2 + BH;           // loads per thread per half-stage
    __shared__ u16 As[2][2][256 * 32];   // [buf][khalf][row*32 + slot*8]
    __shared__ u16 Bs[2][2][BN * 32];
    const int tid  = threadIdx.x;
    const int wid  = tid >> 6;
    const int lane = tid & 63;
    const int wm = wid >> 2, wn = wid & 3;
    const int lr = lane & 15, lg = lane >> 4;
    const u16* Ab = A + (long)blockIdx.y * 256 * lda;
    const u16* Bb = Bt + (long)blockIdx.x * BN * ldb;

    // per-lane pre-swizzled source octet (matches read slot lg ^ ((lr>>1)&3))
    const int swsrc = (((lane & 3) ^ ((lane >> 3) & 3)) * 8) + ((lane >> 2) == 0 ? 0 : 0);
    const int lrow  = lane >> 2;         // row within 16-row chunk

    f32x4 acc[8][FN] = {};

    auto stage = [&](int buf, int kh, int kt) {
        const int kb = kt * 64 + kh * 32 + swsrc;
#pragma unroll
        for (int i = 0; i < 2; ++i) {
            const int c = wid * 2 + i;   // 16-row chunk of A
            __builtin_amdgcn_global_load_lds(
                (gas_ptr)(Ab + (long)(c * 16 + lrow) * lda + kb),
                (las_ptr)&As[buf][kh][c * 512], 16, 0, 0);
        }
#pragma unroll
        for (int i = 0; i < BH; ++i) {
            const int c = wid * BH + i;  // 16-row chunk of B
            __builtin_amdgcn_global_load_lds(
                (gas_ptr)(Bb + (long)(c * 16 + lrow) * ldb + kb),
                (las_ptr)&Bs[buf][kh][c * 512], 16, 0, 0);
        }
    };

    auto compute = [&](int buf, int kh) {
        const int slot8 = ((lg ^ ((lr >> 1) & 3)) * 8);
        bf16x8 af[8], bv[FN];
#pragma unroll
        for (int m = 0; m < 8; ++m)
            af[m] = *(const bf16x8*)&As[buf][kh][(wm * 128 + m * 16 + lr) * 32 + slot8];
#pragma unroll
        for (int n = 0; n < FN; ++n)
            bv[n] = *(const bf16x8*)&Bs[buf][kh][(wn * (FN * 16) + n * 16 + lr) * 32 + slot8];
        __builtin_amdgcn_s_setprio(1);
#pragma unroll
        for (int m = 0; m < 8; ++m)
#pragma unroll
            for (int n = 0; n < FN; ++n)
                acc[m][n] = __builtin_amdgcn_mfma_f32_16x16x32_bf16(af[m], bv[n], acc[m][n], 0, 0, 0);
        __builtin_amdgcn_s_setprio(0);
    };

    const int nt = K / 64;
    // prologue: 3 half-stages in flight
    stage(0, 0, 0);
    stage(0, 1, 0);
    stage(1, 0, 1);

    for (int t = 0; t < nt; ++t) {
        const int buf = t & 1;
        vwait(t < nt - 1 ? 2 * L : L);          // (t,kh0) landed; keep rest in flight
        __builtin_amdgcn_s_barrier();
        if (t < nt - 1) stage(buf ^ 1, 1, t + 1);
        compute(buf, 0);
        vwait(t < nt - 1 ? 2 * L : 0);          // (t,kh1) landed
        __builtin_amdgcn_s_barrier();
        if (t + 2 < nt) stage(buf, 0, t + 2);   // overwrites (t,kh0) region: all waves past it
        compute(buf, 1);
    }

    const int cbase = blockIdx.x * BN + wn * (FN * 16);
    const int rbase = blockIdx.y * 256 + wm * 128;
#pragma unroll
    for (int n = 0; n < FN; ++n) {
        const int c = cbase + n * 16 + lr;
        const float bval = bias ? bias[c] : 0.0f;
#pragma unroll
        for (int m = 0; m < 8; ++m) {
#pragma unroll
            for (int j = 0; j < 4; ++j) {
                const int r = rbase + m * 16 + lg * 4 + j;
                if (r >= rows_valid) continue;
                float v = acc[m][n][j] + bval;
                if constexpr (GELU) v = 0.5f * v * (1.0f + erff(v * 0.70710678118654752f));
                long idx;
                if constexpr (OUTMODE == 1) {
                    const int pb = r / 576, pt = r - pb * 576;
                    v += pos[(long)(1 + pt) * DMODEL + c];
                    idx = (long)(pb * TOKENS + 1 + pt) * ldc + c;
                } else {
                    idx = (long)r * ldc + c;
                }
                if (Cf) Cf[idx] = v;
                if (Cb) Cb[idx] = __float2bfloat16(v);
            }
        }
    }
}

// ---------------------------------------------------------------------------
// Fused flash attention. Grid: (5 q-tiles, NP pairs). 256 threads = 4 waves.
// qkv layout (permuted): [row][ kk*512 + h*128 + d ], row = b*577 + t (+pad).
// ---------------------------------------------------------------------------
__global__ __launch_bounds__(256, 2)
void attn_flash(const u16* __restrict__ qkv, const u16* __restrict__ vhT,
                bf16* __restrict__ ob)
{
    __shared__ u16 ldsA[128 * 128];   // K tile, then P tile
    __shared__ u16 ldsB[128 * 128];   // V^T tile [d][kv]
    const int tid = threadIdx.x;
    const int w = tid >> 6, lane = tid & 63;
    const int lr = lane & 15, lg = lane >> 4;
    const int pair = blockIdx.y;
    const int b = pair >> 2, h = pair & 3;
    const int q0 = blockIdx.x * 128;
    const long rowbase = (long)b * TOKENS;

    bf16x8 qf[2][4];
#pragma unroll
    for (int m = 0; m < 2; ++m)
#pragma unroll
        for (int kf = 0; kf < 4; ++kf) {
            const long r = rowbase + q0 + w * 32 + m * 16 + lr;
            qf[m][kf] = *(const bf16x8*)&qkv[r * 1536 + h * 128 + kf * 32 + lg * 8];
        }

    float mrun[2][4], lrun[2][4];
#pragma unroll
    for (int m = 0; m < 2; ++m)
#pragma unroll
        for (int j = 0; j < 4; ++j) { mrun[m][j] = -1e30f; lrun[m][j] = 0.f; }
    f32x4 oacc[2][8] = {};

    for (int kv0 = 0; kv0 < TPAD; kv0 += 128) {
        {
            const u16* kg = qkv + (rowbase + kv0) * 1536 + 512 + h * 128;
            const u16* vg = vhT + ((long)pair * 128) * TPAD + kv0;
#pragma unroll
            for (int p = 0; p < 8; ++p) {
                const int i = p * 16 + w * 4 + lg;
                __builtin_amdgcn_global_load_lds((gas_ptr)(kg + (long)i * 1536 + lr * 8),
                                                 (las_ptr)&ldsA[(p * 16 + w * 4) * 128], 16, 0, 0);
                __builtin_amdgcn_global_load_lds((gas_ptr)(vg + (long)i * TPAD + lr * 8),
                                                 (las_ptr)&ldsB[(p * 16 + w * 4) * 128], 16, 0, 0);
            }
        }
        __syncthreads();

        f32x4 s[2][8] = {};
#pragma unroll
        for (int kf = 0; kf < 4; ++kf) {
            bf16x8 bv[8];
#pragma unroll
            for (int n = 0; n < 8; ++n)
                bv[n] = *(const bf16x8*)&ldsA[(n * 16 + lr) * 128 + kf * 32 + lg * 8];
            __builtin_amdgcn_s_setprio(1);
#pragma unroll
            for (int m = 0; m < 2; ++m)
#pragma unroll
                for (int n = 0; n < 8; ++n)
                    s[m][n] = __builtin_amdgcn_mfma_f32_16x16x32_bf16(qf[m][kf], bv[n], s[m][n], 0, 0, 0);
            __builtin_amdgcn_s_setprio(0);
        }

        float sc[2][4];
#pragma unroll
        for (int m = 0; m < 2; ++m)
#pragma unroll
            for (int jj = 0; jj < 4; ++jj) {
                float mx = mrun[m][jj];
#pragma unroll
                for (int n = 0; n < 8; ++n) {
                    const int col = kv0 + n * 16 + lr;
                    float v = s[m][n][jj] * SM_SCALE;
                    v = (col < TOKENS) ? v : -1e30f;
                    s[m][n][jj] = v;
                    mx = fmaxf(mx, v);
                }
#pragma unroll
                for (int o = 1; o < 16; o <<= 1) mx = fmaxf(mx, __shfl_xor(mx, o));
                const float f = __expf(mrun[m][jj] - mx);
                sc[m][jj] = f;
                float sum = 0.f;
#pragma unroll
                for (int n = 0; n < 8; ++n) {
                    const float p = __expf(s[m][n][jj] - mx);
                    s[m][n][jj] = p;
                    sum += p;
                }
#pragma unroll
                for (int o = 1; o < 16; o <<= 1) sum += __shfl_xor(sum, o);
                lrun[m][jj] = lrun[m][jj] * f + sum;
                mrun[m][jj] = mx;
            }
#pragma unroll
        for (int m = 0; m < 2; ++m)
#pragma unroll
            for (int n = 0; n < 8; ++n)
#pragma unroll
                for (int jj = 0; jj < 4; ++jj) oacc[m][n][jj] *= sc[m][jj];

        __syncthreads();
#pragma unroll
        for (int m = 0; m < 2; ++m)
#pragma unroll
            for (int n = 0; n < 8; ++n)
#pragma unroll
                for (int jj = 0; jj < 4; ++jj)
                    ldsA[(w * 32 + m * 16 + lg * 4 + jj) * 128 + n * 16 + lr] = f2b(s[m][n][jj]);
        __syncthreads();

#pragma unroll
        for (int kf = 0; kf < 4; ++kf) {
            bf16x8 pa[2];
#pragma unroll
            for (int m = 0; m < 2; ++m)
                pa[m] = *(const bf16x8*)&ldsA[(w * 32 + m * 16 + lr) * 128 + kf * 32 + lg * 8];
            __builtin_amdgcn_s_setprio(1);
#pragma unroll
            for (int n = 0; n < 8; ++n) {
                const bf16x8 vb = *(const bf16x8*)&ldsB[(n * 16 + lr) * 128 + kf * 32 + lg * 8];
#pragma unroll
                for (int m = 0; m < 2; ++m)
                    oacc[m][n] = __builtin_amdgcn_mfma_f32_16x16x32_bf16(pa[m], vb, oacc[m][n], 0, 0, 0);
            }
            __builtin_amdgcn_s_setprio(0);
        }
        __syncthreads();
    }

#pragma unroll
    for (int m = 0; m < 2; ++m)
#pragma unroll
        for (int jj = 0; jj < 4; ++jj) {
            const float inv = 1.f / lrun[m][jj];
            const int q = q0 + w * 32 + m * 16 + lg * 4 + jj;
            if (q >= TOKENS) continue;
#pragma unroll
            for (int n = 0; n < 8; ++n)
                ob[(rowbase + q) * DMODEL + h * 128 + n * 16 + lr] =
                    __float2bfloat16(oacc[m][n][jj] * inv);
        }
}

// ---------------------------------------------------------------------------
// Weight transpose + f32->bf16:  WT[n][k] = bf16(W[k][n]).
// QKVPERM: output row n' = kk*512 + h*128 + d  for original col n = d*12+kk*4+h
// ---------------------------------------------------------------------------
template<bool QKVPERM>
__global__ __launch_bounds__(256)
void wtrans(const float* __restrict__ W, bf16* __restrict__ WT, int K, int N)
{
    __shared__ float tile[32][33];
    const int n0 = blockIdx.x * 32, k0 = blockIdx.y * 32;
    const int tx = threadIdx.x & 31, ty = threadIdx.x >> 5;
#pragma unroll
    for (int i = 0; i < 4; ++i)
        tile[ty + i * 8][tx] = W[(long)(k0 + ty + i * 8) * N + n0 + tx];
    __syncthreads();
#pragma unroll
    for (int i = 0; i < 4; ++i) {
        int n = n0 + ty + i * 8;
        if constexpr (QKVPERM) {
            const int d = n / 12, r = n % 12;
            n = (r >> 2) * 512 + (r & 3) * 128 + d;
        }
        WT[(long)n * K + k0 + tx] = __float2bfloat16(tile[tx][ty + i * 8]);
    }
}

// ---------------------------------------------------------------------------
// Patch gather: img (Bc,3,384,384) -> pat[b*576 + x*24+y][p1*48 + p2*3 + c] bf16
// ---------------------------------------------------------------------------
__global__ __launch_bounds__(64)
void patch_gather(const float* __restrict__ img, bf16* __restrict__ pat)
{
    const int bid = blockIdx.x;
    const int x  = bid % 24;
    const int p1 = (bid / 24) % 16;
    const int b  = bid / (24 * 16);
    __shared__ bf16 lds[24][48];
    const int lane = threadIdx.x;
    const int h = p1 * 24 + x;
    for (int c = 0; c < 3; ++c) {
        const float* row = img + ((long)(b * 3 + c) * 384 + h) * 384;
#pragma unroll
        for (int i = 0; i < 6; ++i) {
            const int wpix = lane + i * 64;
            const float v = row[wpix];
            const int y = wpix % 24, p2 = wpix / 24;
            lds[y][p2 * 3 + c] = __float2bfloat16(v);
        }
    }
    __syncthreads();
    for (int idx = lane; idx < 24 * 48; idx += 64) {
        const int y = idx / 48, j = idx % 48;
        pat[(long)(b * 576 + x * 24 + y) * 768 + p1 * 48 + j] = lds[y][j];
    }
}

// cls token row
__global__ __launch_bounds__(256)
void clsfill(const float* __restrict__ cls, const float* __restrict__ pos,
             float* __restrict__ tokf, bf16* __restrict__ xb)
{
    const int i = blockIdx.x * 256 + threadIdx.x;
    const int b = i >> 9, d = i & 511;
    const float v = cls[d] + pos[d];
    tokf[(long)b * TOKENS * DMODEL + d] = v;
    xb[(long)b * TOKENS * DMODEL + d] = __float2bfloat16(v);
}

// ---------------------------------------------------------------------------
// v (qkv permuted col 1024 + h*128 + d) -> vhT[(pair)*128 + d][t], t>=577 -> 0
// ---------------------------------------------------------------------------
__global__ __launch_bounds__(256)
void repack_v(const u16* __restrict__ qkv, u16* __restrict__ vhT)
{
    __shared__ u16 lds[64][136];
    const int bid = blockIdx.x;               // (pair, tt)
    const int tt = bid % 10, pair = bid / 10;
    const int b = pair >> 2, h = pair & 3;
    const int tid = threadIdx.x;
    const int tl = tid >> 2, seg = tid & 3;
    const long row = (long)b * TOKENS + tt * 64 + tl;
    const u16* src = qkv + row * 1536 + 1024 + h * 128 + seg * 32;
#pragma unroll
    for (int u = 0; u < 4; ++u)
        *(uint4*)&lds[tl][seg * 32 + u * 8] = *(const uint4*)&src[u * 8];
    __syncthreads();
    const int d = tid >> 1, th = (tid & 1) * 32;
    u16* dst = vhT + ((long)pair * 128 + d) * TPAD + tt * 64 + th;
#pragma unroll
    for (int blk = 0; blk < 4; ++blk) {
        uint4 pk; u16* pp = (u16*)&pk;
#pragma unroll
        for (int j = 0; j < 8; ++j) {
            const int t = tt * 64 + th + blk * 8 + j;
            pp[j] = (t < TOKENS) ? lds[th + blk * 8 + j][d] : (u16)0;
        }
        *(uint4*)&dst[blk * 8] = pk;
    }
}

// ---------------------------------------------------------------------------
// y = LN(xin + res)*g + b  -> outf (may alias res) and outb (bf16)
// ---------------------------------------------------------------------------
__global__ __launch_bounds__(256)
void resln(const float* __restrict__ xin, const float* __restrict__ res,
           const float* __restrict__ g, const float* __restrict__ b,
           float* __restrict__ outf, bf16* __restrict__ outb, int nrows)
{
    const int row = blockIdx.x * 4 + (threadIdx.x >> 6);
    if (row >= nrows) return;
    const int lane = threadIdx.x & 63;
    const float* p1 = xin + (long)row * DMODEL;
    const float* p2 = res + (long)row * DMODEL;
    float v[8];
    float s = 0.f;
#pragma unroll
    for (int i = 0; i < 8; ++i) { v[i] = p1[lane + i * 64] + p2[lane + i * 64]; s += v[i]; }
#pragma unroll
    for (int o = 32; o; o >>= 1) s += __shfl_xor(s, o);
    const float mean = s * (1.f / 512.f);
    float q = 0.f;
#pragma unroll
    for (int i = 0; i < 8; ++i) { const float d = v[i] - mean; q += d * d; }
#pragma unroll
    for (int o = 32; o; o >>= 1) q += __shfl_xor(q, o);
    const float rs = rsqrtf(q * (1.f / 512.f) + 1e-5f);
#pragma unroll
    for (int i = 0; i < 8; ++i) {
        const int c = lane + i * 64;
        const float o = (v[i] - mean) * rs * g[c] + b[c];
        outf[(long)row * DMODEL + c] = o;
        outb[(long)row * DMODEL + c] = __float2bfloat16(o);
    }
}

// Head: out[b][c] = tok[b*577][:] . Whead[:,c] + bhead[c]
__global__ __launch_bounds__(64)
void head_k(const float* __restrict__ tokf, const float* __restrict__ Wh,
            const float* __restrict__ bh, float* __restrict__ out)
{
    const int b = blockIdx.x;
    const int lane = threadIdx.x;
    const float* x = tokf + (long)b * TOKENS * DMODEL;
    float acc[10] = {};
#pragma unroll
    for (int i = 0; i < 8; ++i) {
        const int d = lane + i * 64;
        const float xv = x[d];
        const float* wr = Wh + (long)d * 10;
#pragma unroll
        for (int c = 0; c < 10; ++c) acc[c] += xv * wr[c];
    }
#pragma unroll
    for (int c = 0; c < 10; ++c)
#pragma unroll
        for (int o = 32; o; o >>= 1) acc[c] += __shfl_xor(acc[c], o);
    if (lane == 0) {
#pragma unroll
        for (int c = 0; c < 10; ++c) out[b * 10 + c] = acc[c] + bh[c];
    }
}

// ---------------------------------------------------------------------------
extern "C" void kernel_launch(void* const* d_in, const int* in_sizes, int n_in,
                              void* d_out, int out_size, void* d_ws, size_t ws_size,
                              hipStream_t stream)
{
    (void)in_sizes; (void)n_in; (void)out_size;
    const float* img    = (const float*)d_in[0];
    const float* Wpatch = (const float*)d_in[1];
    const float* bpatch = (const float*)d_in[2];
    const float* clstk  = (const float*)d_in[3];
    const float* pos    = (const float*)d_in[4];
    const float* Wqkv   = (const float*)d_in[5];
    const float* W0     = (const float*)d_in[6];
    const float* g1     = (const float*)d_in[7];
    const float* b1     = (const float*)d_in[8];
    const float* g2     = (const float*)d_in[9];
    const float* b2     = (const float*)d_in[10];
    const float* W1     = (const float*)d_in[11];
    const float* bb1    = (const float*)d_in[12];
    const float* W2     = (const float*)d_in[13];
    const float* bb2    = (const float*)d_in[14];
    const float* Whead  = (const float*)d_in[15];
    const float* bhead  = (const float*)d_in[16];

    // ---- pick the largest batch chunk that fits ws (M padded to 256) ----
    static const int cand[6] = {32, 16, 8, 4, 2, 1};
    int Bc = 0;
    size_t o_tokf=0, o_xb=0, o_R1=0, o_R2=0, o_ob=0, o_wp=0, o_wr=0;
    for (int ci = 0; ci < 6; ++ci) {
        const int bc = cand[ci];
        const long Mrows = (long)bc * TOKENS;
        const long Mpad  = ((Mrows + 255) / 256) * 256;
        size_t off = 0;
        auto take = [&](size_t sz) { size_t o = off; off += (sz + 255) & ~(size_t)255; return o; };
        size_t t_tokf = take((size_t)Mpad * 512 * 4);
        size_t t_xb   = take((size_t)Mpad * 512 * 2);
        size_t t_R1   = take((size_t)Mpad * 2048 * 2);          // pat | qkv | h1b
        size_t t_R2   = take((size_t)Mpad * 512 * 4);           // vhT | t1
        size_t t_ob   = take((size_t)Mpad * 512 * 2);
        size_t t_wp   = take((size_t)512 * 768 * 2);
        size_t t_wr   = take((size_t)3145728 * 2);              // rotating layer weights
        if (off <= ws_size) {
            Bc = bc;
            o_tokf=t_tokf; o_xb=t_xb; o_R1=t_R1; o_R2=t_R2; o_ob=t_ob; o_wp=t_wp; o_wr=t_wr;
            break;
        }
    }
    if (Bc == 0) return;

    const long Mrows = (long)Bc * TOKENS;
    const long Mpad  = ((Mrows + 255) / 256) * 256;
    const int  NP    = Bc * 4;
    const int  gy    = (int)(Mpad / 256);
    const int  gyp   = (int)(((long)Bc * 576 + 255) / 256);

    char* base = (char*)d_ws;
    float* tokf = (float*)(base + o_tokf);
    bf16*  xb   = (bf16*)(base + o_xb);
    char*  R1   = base + o_R1;
    char*  R2   = base + o_R2;
    bf16*  ob   = (bf16*)(base + o_ob);
    bf16*  wpT  = (bf16*)(base + o_wp);
    bf16*  wqkvT = (bf16*)(base + o_wr);
    bf16*  w0T   = wqkvT + 1536 * 512;
    bf16*  w1T   = w0T   + 512 * 512;
    bf16*  w2T   = w1T   + 2048 * 512;

    u16*  qkvb = (u16*)R1;
    bf16* pat  = (bf16*)R1;
    u16*  h1b  = (u16*)R1;
    u16*  vhT  = (u16*)R2;
    float* t1  = (float*)R2;

    wtrans<false><<<dim3(512 / 32, 768 / 32), 256, 0, stream>>>(Wpatch, wpT, 768, 512);

    const int nchunks = 32 / Bc;
    for (int ch = 0; ch < nchunks; ++ch) {
        const float* img_c = img + (long)ch * Bc * 3 * 384 * 384;

        // embed
        hipMemsetAsync(xb, 0, (size_t)Mpad * 512 * 2, stream);   // pad rows -> exact 0
        clsfill<<<Bc * 2, 256, 0, stream>>>(clstk, pos, tokf, xb);
        patch_gather<<<Bc * 16 * 24, 64, 0, stream>>>(img_c, pat);
        gemm2<1, false, 128><<<dim3(4, gyp), 512, 0, stream>>>(
            (const u16*)pat, 768, (const u16*)wpT, 768,
            tokf, xb, 512, bpatch, pos, 768, Bc * 576);

        for (int l = 0; l < 6; ++l) {
            // rotate this layer's weights to bf16 N x K (Wqkv column-permuted)
            wtrans<true ><<<dim3(1536 / 32, 512 / 32), 256, 0, stream>>>(
                Wqkv + (long)l * 512 * 1536, wqkvT, 512, 1536);
            wtrans<false><<<dim3(512 / 32, 512 / 32), 256, 0, stream>>>(
                W0 + (long)l * 512 * 512, w0T, 512, 512);
            wtrans<false><<<dim3(2048 / 32, 512 / 32), 256, 0, stream>>>(
                W1 + (long)l * 512 * 2048, w1T, 512, 2048);
            wtrans<false><<<dim3(512 / 32, 2048 / 32), 256, 0, stream>>>(
                W2 + (long)l * 2048 * 512, w2T, 2048, 512);

            // qkv = x @ Wqkv  (permuted cols: kk*512 + h*128 + d)
            gemm2<0, false, 256><<<dim3(6, gy), 512, 0, stream>>>(
                (const u16*)xb, 512, (const u16*)wqkvT, 512,
                nullptr, (bf16*)qkvb, 1536, nullptr, nullptr, 512, (int)Mpad);

            repack_v<<<NP * 10, 256, 0, stream>>>(qkvb, vhT);
            attn_flash<<<dim3(5, NP), 256, 0, stream>>>(qkvb, vhT, ob);

            // proj: t1 = o @ W0   (t1 overwrites vhT — attention done)
            gemm2<0, false, 128><<<dim3(4, gy), 512, 0, stream>>>(
                (const u16*)ob, 512, (const u16*)w0T, 512,
                t1, nullptr, 512, nullptr, nullptr, 512, (int)Mrows);
            resln<<<(int)((Mrows + 3) / 4), 256, 0, stream>>>(
                t1, tokf, g1 + l * 512, b1 + l * 512, tokf, xb, (int)Mrows);
            // h1 = gelu(y @ W1 + bb1)   (h1b overwrites qkv — dead)
            gemm2<0, true, 256><<<dim3(8, gy), 512, 0, stream>>>(
                (const u16*)xb, 512, (const u16*)w1T, 512,
                nullptr, (bf16*)h1b, 2048, bb1 + l * 2048, nullptr, 512, (int)Mpad);
            // t1 = h1 @ W2 + bb2
            gemm2<0, false, 128><<<dim3(4, gy), 512, 0, stream>>>(
                (const u16*)h1b, 2048, (const u16*)w2T, 2048,
                t1, nullptr, 512, bb2 + l * 512, nullptr, 2048, (int)Mrows);
            resln<<<(int)((Mrows + 3) / 4), 256, 0, stream>>>(
                t1, tokf, g2 + l * 512, b2 + l * 512, tokf, xb, (int)Mrows);
        }

        head_k<<<Bc, 64, 0, stream>>>(tokf, Whead, bhead, (float*)d_out + (long)ch * Bc * 10);
    }
}